// Round 2
// baseline (122.363 us; speedup 1.0000x reference)
//
#include <hip/hip_runtime.h>
#include <cstdint>
#include <cstddef>

#define NB 8
#define NS 2048
#define ND 768
#define NSP 512
#define MAXW 30
#define NH 100
#define LDP 104        // P row stride in floats (26 float4)
#define NKS 24         // 768 / 32 k-steps
#define NCF 8          // 8 col-frags of 16 (cols 0..99 = h, 100 = logit, 101..127 = 0)
#define BM 16          // proj rows per block tile
#define NIT 12         // proj outer iters (BK = 64)

typedef __attribute__((ext_vector_type(8))) _Float16 half8;
typedef __attribute__((ext_vector_type(2))) __fp16 fp16x2;
typedef __attribute__((ext_vector_type(4))) float floatx4;

union U4H8 { uint4 v; half8 h8; unsigned u[4]; unsigned short us[8]; };
union H2U  { fp16x2 h; unsigned u; };

__device__ inline unsigned short f2h(float f) {   // RNE f32->f16 (pack, cold path)
    _Float16 h = (_Float16)f;
    union { _Float16 hh; unsigned short us; } c; c.hh = h;
    return c.us;
}

// Kernel 0: pack B = [ffnn_w | att_w | 0] (768 x 128) into MFMA B-frag order, f16.
// Frag (ks, cf) at (ks*8+cf)*64: lane l holds B[ks*32 + (l>>4)*8 + j][cf*16 + (l&15)].
// One 64-lane wave per (ks, cf) frag: 192 blocks (was 24 -> 8x CU coverage).
__global__ __launch_bounds__(64) void pack_b_kernel(
    const float* __restrict__ ffnn_w, const float* __restrict__ att_w,
    uint4* __restrict__ Bfrag)
{
    const int ks = blockIdx.x >> 3, cf = blockIdx.x & 7;
    const int lane = threadIdx.x;
    const int q = lane >> 4, r = lane & 15;
    const int n = cf * 16 + r;
    U4H8 p;
#pragma unroll
    for (int j = 0; j < 8; j++) {
        int k = ks * 32 + q * 8 + j;
        float v = (n < NH) ? ffnn_w[(size_t)k * NH + n]
                           : (n == NH ? att_w[k] : 0.f);
        p.us[j] = f2h(v);
    }
    Bfrag[(size_t)(ks * NCF + cf) * 64 + lane] = p.v;
}

// Kernel 1: proj in f16. 1024 blocks x 256 threads (16 waves/CU). Tile 16 rows
// x 128 cols; A converted f32->f16 via v_cvt_pkrtz at staging into a
// DOUBLE-BUFFERED LDS array (2 x 2.3 KB) -> ONE barrier per K-iter (WAR on
// buf (i&1) is protected by iter i-1's barrier: every thread's tile-(i-2)
// reads precede its iter-(i-1) barrier in program order). seq is read-once ->
// nontemporal loads keep Bfrag/P resident in L2. B register-direct from L2,
// depth-1 prefetch. Writes P cols 0..99 and Lg (col 100 = attention logit).
__global__ __launch_bounds__(256, 4) void proj_kernel(
    const float* __restrict__ seq, const uint4* __restrict__ Bfrag,
    float* __restrict__ P, float* __restrict__ Lg)
{
    __shared__ unsigned Ah[2][BM][36];  // f16 pairs; 64 k/row = 32 uints + 4 pad
    const int t = threadIdx.x;
    const int wave = t >> 6, lane = t & 63;
    const int q = lane >> 4, r = lane & 15;
    const int cf0 = wave * 2;
    const int row0 = blockIdx.x * BM;

    floatx4 acc[2] = {{0.f,0.f,0.f,0.f},{0.f,0.f,0.f,0.f}};

    const int sr = t >> 4, sc = t & 15;
    const floatx4* gA = (const floatx4*)(seq + (size_t)(row0 + sr) * ND);
    floatx4 sv = __builtin_nontemporal_load(gA + sc);

    const uint4* bp = Bfrag + (size_t)cf0 * 64 + lane;
    uint4 Bc0 = bp[0], Bc1 = bp[64], Bc2 = bp[512], Bc3 = bp[512 + 64];

    for (int i = 0; i < NIT; ++i) {
        H2U u01, u23;
        u01.h = __builtin_amdgcn_cvt_pkrtz(sv.x, sv.y);
        u23.h = __builtin_amdgcn_cvt_pkrtz(sv.z, sv.w);
        { uint2 u; u.x = u01.u; u.y = u23.u; *(uint2*)&Ah[i & 1][sr][sc * 2] = u; }
        __syncthreads();                     // tile i visible (single barrier/iter)

        const int ni = (i + 1 < NIT) ? i + 1 : i;
        sv = __builtin_nontemporal_load(gA + ni * 16 + sc);   // prefetch A tile i+1
        const size_t nb = (size_t)ni * 1024;
        uint4 Bn0 = bp[nb], Bn1 = bp[nb + 64], Bn2 = bp[nb + 512], Bn3 = bp[nb + 512 + 64];

#pragma unroll
        for (int ksl = 0; ksl < 2; ++ksl) {
            U4H8 a, b0, b1;
            a.v  = *(const uint4*)&Ah[i & 1][r][ksl * 16 + q * 4];
            b0.v = ksl ? Bc2 : Bc0;
            b1.v = ksl ? Bc3 : Bc1;
            acc[0] = __builtin_amdgcn_mfma_f32_16x16x32_f16(a.h8, b0.h8, acc[0], 0, 0, 0);
            acc[1] = __builtin_amdgcn_mfma_f32_16x16x32_f16(a.h8, b1.h8, acc[1], 0, 0, 0);
        }
        Bc0 = Bn0; Bc1 = Bn1; Bc2 = Bn2; Bc3 = Bn3;
    }

    // C/D layout: col = (cf0+c)*16 + r, row = row0 + q*4 + reg
#pragma unroll
    for (int c = 0; c < 2; ++c) {
        const int col = (cf0 + c) * 16 + r;
        const int rowb = row0 + q * 4;
        if (col < NH) {
#pragma unroll
            for (int reg = 0; reg < 4; ++reg)
                P[(size_t)(rowb + reg) * LDP + col] = acc[c][reg];
        } else if (col == NH) {
#pragma unroll
            for (int reg = 0; reg < 4; ++reg)
                Lg[rowb + reg] = acc[c][reg];
        }
    }
}

// Kernel 2: TWO spans per wave (half-wave each, width-32 shuffles) -> 2x
// independent load streams per wave. Loads predicated on i<w (half-uniform
// exec mask). Softmax over Lg (att_b cancels); fused bias+mask+tanh.
__global__ __launch_bounds__(256, 4) void span_kernel(
    const int* __restrict__ span_idx, const int* __restrict__ span_mask,
    const float* __restrict__ P, const float* __restrict__ Lg,
    const float* __restrict__ ffnn_b, float* __restrict__ out)
{
    const int hw = threadIdx.x >> 5, lane = threadIdx.x & 31;
    const int gs = blockIdx.x * 8 + hw;            // [0, 4096)
    const int b = gs / NSP;
    const int st = span_idx[2 * gs];
    int w = span_idx[2 * gs + 1] - st;             // width in [1, MAXW]
    w = max(1, min(w, MAXW));

    float lg = (lane < w) ? Lg[b * NS + st + lane] : -1e30f;
    float mx = lg;
#pragma unroll
    for (int off = 16; off > 0; off >>= 1) mx = fmaxf(mx, __shfl_xor(mx, off, 32));
    float e = (lane < w) ? __expf(lg - mx) : 0.f;
    float sum = e;
#pragma unroll
    for (int off = 16; off > 0; off >>= 1) sum += __shfl_xor(sum, off, 32);
    float attn = e / sum;                          // 0 for lanes >= w

    int cl = min(lane, 24);
    const float4* Pb4 = (const float4*)(P + ((size_t)b * NS + st) * LDP) + cl;
    float4 acc = {0.f, 0.f, 0.f, 0.f};
#pragma unroll
    for (int i = 0; i < MAXW; ++i) {
        float a = __shfl(attn, i, 32);
        if (i < w) {                               // half-uniform predicate
            float4 v = Pb4[i * (LDP / 4)];
            acc.x += a * v.x; acc.y += a * v.y; acc.z += a * v.z; acc.w += a * v.w;
        }
    }

    if (lane < 25) {
        float m = (float)span_mask[gs];
        float4 bias = ((const float4*)ffnn_b)[lane];
        float4 o;
        o.x = tanhf(m * acc.x + bias.x);
        o.y = tanhf(m * acc.y + bias.y);
        o.z = tanhf(m * acc.z + bias.z);
        o.w = tanhf(m * acc.w + bias.w);
        *(float4*)(out + (size_t)gs * NH + 4 * lane) = o;
    }
}

extern "C" void kernel_launch(void* const* d_in, const int* in_sizes, int n_in,
                              void* d_out, int out_size, void* d_ws, size_t ws_size,
                              hipStream_t stream) {
    const float* seq      = (const float*)d_in[0];  // [B,S,D]
    const int*   span_idx = (const int*)d_in[1];    // [B,N,2] int32 on device
    const int*   span_msk = (const int*)d_in[2];    // [B,N]
    const float* att_w    = (const float*)d_in[3];  // [D,1]
    // d_in[4] = att_b: cancels inside softmax — unused
    const float* ffnn_w   = (const float*)d_in[5];  // [D,H]
    const float* ffnn_b   = (const float*)d_in[6];  // [H]
    float* out = (float*)d_out;                     // [B,N,H]

    char* ws = (char*)d_ws;
    size_t off = 0;
    float* P     = (float*)(ws + off); off += (size_t)NB * NS * LDP * 4;    // 6.82 MB
    uint4* Bfrag = (uint4*)(ws + off); off += (size_t)NKS * NCF * 64 * 16;  // 192 KB
    float* Lg    = (float*)(ws + off);                                      // 64 KB

    pack_b_kernel<<<NKS * NCF, 64, 0, stream>>>(ffnn_w, att_w, Bfrag);
    proj_kernel<<<(NB * NS) / BM, 256, 0, stream>>>(seq, Bfrag, P, Lg);
    span_kernel<<<(NB * NSP) / 8, 256, 0, stream>>>(span_idx, span_msk, P, Lg, ffnn_b, out);
}

// Round 3
// 113.818 us; speedup vs baseline: 1.0751x; 1.0751x over previous
//
#include <hip/hip_runtime.h>
#include <cstdint>
#include <cstddef>

#define NB 8
#define NS 2048
#define ND 768
#define NSP 512
#define MAXW 30
#define NH 100
#define LDP 104        // P row stride in floats (26 float4)
#define NKS 24         // 768 / 32 k-steps
#define NCF 8          // 8 col-frags of 16 (cols 0..99 = h, 100 = logit, 101..127 = 0)
#define BM 32          // proj rows per block tile (was 16; halves B L2 traffic)
#define NIT 12         // proj outer iters (BK = 64)

typedef __attribute__((ext_vector_type(8))) _Float16 half8;
typedef __attribute__((ext_vector_type(2))) __fp16 fp16x2;
typedef __attribute__((ext_vector_type(4))) float floatx4;

union U4H8 { uint4 v; half8 h8; unsigned u[4]; unsigned short us[8]; };
union H2U  { fp16x2 h; unsigned u; };

__device__ inline unsigned short f2h(float f) {   // RNE f32->f16 (pack, cold path)
    _Float16 h = (_Float16)f;
    union { _Float16 hh; unsigned short us; } c; c.hh = h;
    return c.us;
}

// Kernel 0: pack B = [ffnn_w | att_w | 0] (768 x 128) into MFMA B-frag order, f16.
// Frag (ks, cf) at (ks*8+cf)*64: lane l holds B[ks*32 + (l>>4)*8 + j][cf*16 + (l&15)].
// One 64-lane wave per (ks, cf) frag: 192 blocks.
__global__ __launch_bounds__(64) void pack_b_kernel(
    const float* __restrict__ ffnn_w, const float* __restrict__ att_w,
    uint4* __restrict__ Bfrag)
{
    const int ks = blockIdx.x >> 3, cf = blockIdx.x & 7;
    const int lane = threadIdx.x;
    const int q = lane >> 4, r = lane & 15;
    const int n = cf * 16 + r;
    U4H8 p;
#pragma unroll
    for (int j = 0; j < 8; j++) {
        int k = ks * 32 + q * 8 + j;
        float v = (n < NH) ? ffnn_w[(size_t)k * NH + n]
                           : (n == NH ? att_w[k] : 0.f);
        p.us[j] = f2h(v);
    }
    Bfrag[(size_t)(ks * NCF + cf) * 64 + lane] = p.v;
}

// Kernel 1: proj in f16. 512 blocks x 256 threads. Tile 32 rows x 128 cols
// (BM=32 halves per-block-amortized Bfrag L2 traffic: 196 MB -> 98 MB total).
// A converted f32->f16 via v_cvt_pkrtz at staging into a DOUBLE-BUFFERED LDS
// array (2 x 4.5 KB) -> ONE barrier per K-iter (WAR on buf (i&1) is protected
// by iter i-1's barrier). B register-direct from L2, depth-1 prefetch.
// Writes P cols 0..99 and Lg (col 100 = attention logit).
__global__ __launch_bounds__(256, 4) void proj_kernel(
    const float* __restrict__ seq, const uint4* __restrict__ Bfrag,
    float* __restrict__ P, float* __restrict__ Lg)
{
    __shared__ unsigned Ah[2][BM][36];  // f16 pairs; 64 k/row = 32 uints + 4 pad
    const int t = threadIdx.x;
    const int wave = t >> 6, lane = t & 63;
    const int q = lane >> 4, r = lane & 15;
    const int cf0 = wave * 2;
    const int row0 = blockIdx.x * BM;

    floatx4 acc[2][2] = {{{0.f,0.f,0.f,0.f},{0.f,0.f,0.f,0.f}},
                         {{0.f,0.f,0.f,0.f},{0.f,0.f,0.f,0.f}}};

    // staging map: 8 threads/row x 32 rows; each thread loads 2 float4 per iter
    const int sr = t >> 3, sc = t & 7;
    const float4* gA = (const float4*)(seq + (size_t)(row0 + sr) * ND);
    float4 sv0 = gA[sc], sv1 = gA[sc + 8];

    const uint4* bp = Bfrag + (size_t)cf0 * 64 + lane;
    uint4 Bc0 = bp[0], Bc1 = bp[64], Bc2 = bp[512], Bc3 = bp[512 + 64];

    for (int i = 0; i < NIT; ++i) {
        H2U a01, a23, b01, b23;
        a01.h = __builtin_amdgcn_cvt_pkrtz(sv0.x, sv0.y);
        a23.h = __builtin_amdgcn_cvt_pkrtz(sv0.z, sv0.w);
        b01.h = __builtin_amdgcn_cvt_pkrtz(sv1.x, sv1.y);
        b23.h = __builtin_amdgcn_cvt_pkrtz(sv1.z, sv1.w);
        { uint2 u; u.x = a01.u; u.y = a23.u; *(uint2*)&Ah[i & 1][sr][sc * 2] = u; }
        { uint2 u; u.x = b01.u; u.y = b23.u; *(uint2*)&Ah[i & 1][sr][sc * 2 + 16] = u; }
        __syncthreads();                     // tile i visible (single barrier/iter)

        const int ni = (i + 1 < NIT) ? i + 1 : i;
        sv0 = gA[ni * 16 + sc];              // prefetch A tile i+1
        sv1 = gA[ni * 16 + sc + 8];
        const size_t nb = (size_t)ni * 1024;
        uint4 Bn0 = bp[nb], Bn1 = bp[nb + 64], Bn2 = bp[nb + 512], Bn3 = bp[nb + 512 + 64];

#pragma unroll
        for (int ksl = 0; ksl < 2; ++ksl) {
            U4H8 b0, b1;
            b0.v = ksl ? Bc2 : Bc0;
            b1.v = ksl ? Bc3 : Bc1;
#pragma unroll
            for (int rt = 0; rt < 2; ++rt) {
                U4H8 a;
                a.v = *(const uint4*)&Ah[i & 1][rt * 16 + r][ksl * 16 + q * 4];
                acc[rt][0] = __builtin_amdgcn_mfma_f32_16x16x32_f16(a.h8, b0.h8, acc[rt][0], 0, 0, 0);
                acc[rt][1] = __builtin_amdgcn_mfma_f32_16x16x32_f16(a.h8, b1.h8, acc[rt][1], 0, 0, 0);
            }
        }
        Bc0 = Bn0; Bc1 = Bn1; Bc2 = Bn2; Bc3 = Bn3;
    }

    // C/D layout: col = (cf0+c)*16 + r, row = row0 + rt*16 + q*4 + reg
#pragma unroll
    for (int rt = 0; rt < 2; ++rt) {
#pragma unroll
        for (int c = 0; c < 2; ++c) {
            const int col = (cf0 + c) * 16 + r;
            const int rowb = row0 + rt * 16 + q * 4;
            if (col < NH) {
#pragma unroll
                for (int reg = 0; reg < 4; ++reg)
                    P[(size_t)(rowb + reg) * LDP + col] = acc[rt][c][reg];
            } else if (col == NH) {
#pragma unroll
                for (int reg = 0; reg < 4; ++reg)
                    Lg[rowb + reg] = acc[rt][c][reg];
            }
        }
    }
}

// Kernel 2: TWO spans per wave (half-wave each, width-32 shuffles) -> 2x
// independent load streams per wave. Loads predicated on i<w (half-uniform
// exec mask). Softmax over Lg (att_b cancels); fused bias+mask+tanh.
__global__ __launch_bounds__(256, 4) void span_kernel(
    const int* __restrict__ span_idx, const int* __restrict__ span_mask,
    const float* __restrict__ P, const float* __restrict__ Lg,
    const float* __restrict__ ffnn_b, float* __restrict__ out)
{
    const int hw = threadIdx.x >> 5, lane = threadIdx.x & 31;
    const int gs = blockIdx.x * 8 + hw;            // [0, 4096)
    const int b = gs / NSP;
    const int st = span_idx[2 * gs];
    int w = span_idx[2 * gs + 1] - st;             // width in [1, MAXW]
    w = max(1, min(w, MAXW));

    float lg = (lane < w) ? Lg[b * NS + st + lane] : -1e30f;
    float mx = lg;
#pragma unroll
    for (int off = 16; off > 0; off >>= 1) mx = fmaxf(mx, __shfl_xor(mx, off, 32));
    float e = (lane < w) ? __expf(lg - mx) : 0.f;
    float sum = e;
#pragma unroll
    for (int off = 16; off > 0; off >>= 1) sum += __shfl_xor(sum, off, 32);
    float attn = e / sum;                          // 0 for lanes >= w

    int cl = min(lane, 24);
    const float4* Pb4 = (const float4*)(P + ((size_t)b * NS + st) * LDP) + cl;
    float4 acc = {0.f, 0.f, 0.f, 0.f};
#pragma unroll
    for (int i = 0; i < MAXW; ++i) {
        float a = __shfl(attn, i, 32);
        if (i < w) {                               // half-uniform predicate
            float4 v = Pb4[i * (LDP / 4)];
            acc.x += a * v.x; acc.y += a * v.y; acc.z += a * v.z; acc.w += a * v.w;
        }
    }

    if (lane < 25) {
        float m = (float)span_mask[gs];
        float4 bias = ((const float4*)ffnn_b)[lane];
        float4 o;
        o.x = tanhf(m * acc.x + bias.x);
        o.y = tanhf(m * acc.y + bias.y);
        o.z = tanhf(m * acc.z + bias.z);
        o.w = tanhf(m * acc.w + bias.w);
        *(float4*)(out + (size_t)gs * NH + 4 * lane) = o;
    }
}

extern "C" void kernel_launch(void* const* d_in, const int* in_sizes, int n_in,
                              void* d_out, int out_size, void* d_ws, size_t ws_size,
                              hipStream_t stream) {
    const float* seq      = (const float*)d_in[0];  // [B,S,D]
    const int*   span_idx = (const int*)d_in[1];    // [B,N,2] int32 on device
    const int*   span_msk = (const int*)d_in[2];    // [B,N]
    const float* att_w    = (const float*)d_in[3];  // [D,1]
    // d_in[4] = att_b: cancels inside softmax — unused
    const float* ffnn_w   = (const float*)d_in[5];  // [D,H]
    const float* ffnn_b   = (const float*)d_in[6];  // [H]
    float* out = (float*)d_out;                     // [B,N,H]

    char* ws = (char*)d_ws;
    size_t off = 0;
    float* P     = (float*)(ws + off); off += (size_t)NB * NS * LDP * 4;    // 6.82 MB
    uint4* Bfrag = (uint4*)(ws + off); off += (size_t)NKS * NCF * 64 * 16;  // 192 KB
    float* Lg    = (float*)(ws + off);                                      // 64 KB

    pack_b_kernel<<<NKS * NCF, 64, 0, stream>>>(ffnn_w, att_w, Bfrag);
    proj_kernel<<<(NB * NS) / BM, 256, 0, stream>>>(seq, Bfrag, P, Lg);
    span_kernel<<<(NB * NSP) / 8, 256, 0, stream>>>(span_idx, span_msk, P, Lg, ffnn_b, out);
}

// Round 4
// 110.407 us; speedup vs baseline: 1.1083x; 1.0309x over previous
//
#include <hip/hip_runtime.h>
#include <cstdint>
#include <cstddef>

#define NB 8
#define NS 2048
#define ND 768
#define NSP 512
#define MAXW 30
#define NH 100
#define LDP 104        // P row stride in floats (26 float4)
#define NKS 24         // 768 / 32 k-steps
#define NCF 8          // 8 col-frags of 16 (cols 0..99 = h, 100 = logit, 101..127 = 0)
#define BM 32          // proj rows per block tile
#define NIT 12         // proj outer iters (BK = 64)

typedef __attribute__((ext_vector_type(8))) _Float16 half8;
typedef __attribute__((ext_vector_type(2))) __fp16 fp16x2;
typedef __attribute__((ext_vector_type(4))) float floatx4;

union U4H8 { uint4 v; half8 h8; unsigned u[4]; unsigned short us[8]; };
union H2U  { fp16x2 h; unsigned u; };

__device__ inline unsigned short f2h(float f) {   // RNE f32->f16 (pack, cold path)
    _Float16 h = (_Float16)f;
    union { _Float16 hh; unsigned short us; } c; c.hh = h;
    return c.us;
}

// Kernel 0: pack B = [ffnn_w | att_w | 0] (768 x 128) into MFMA B-frag order, f16.
// Frag (ks, cf) at (ks*8+cf)*64: lane l holds B[ks*32 + (l>>4)*8 + j][cf*16 + (l&15)].
// One 64-lane wave per (ks, cf) frag: 192 blocks.
__global__ __launch_bounds__(64) void pack_b_kernel(
    const float* __restrict__ ffnn_w, const float* __restrict__ att_w,
    uint4* __restrict__ Bfrag)
{
    const int ks = blockIdx.x >> 3, cf = blockIdx.x & 7;
    const int lane = threadIdx.x;
    const int q = lane >> 4, r = lane & 15;
    const int n = cf * 16 + r;
    U4H8 p;
#pragma unroll
    for (int j = 0; j < 8; j++) {
        int k = ks * 32 + q * 8 + j;
        float v = (n < NH) ? ffnn_w[(size_t)k * NH + n]
                           : (n == NH ? att_w[k] : 0.f);
        p.us[j] = f2h(v);
    }
    Bfrag[(size_t)(ks * NCF + cf) * 64 + lane] = p.v;
}

// Kernel 1: proj in f16. 512 blocks x 256 threads. Tile 32 rows x 128 cols.
// A converted f32->f16 via v_cvt_pkrtz at staging into a DOUBLE-BUFFERED LDS
// array (2 x 4.5 KB) -> ONE barrier per K-iter (WAR on buf (i&1) is protected
// by iter i-1's barrier). B register-direct from L2, depth-1 prefetch.
// HBM-bound on the 50 MB read-once seq stream (~8.2 us floor) — verified R2.
// Writes P cols 0..99 and Lg (col 100 = attention logit).
__global__ __launch_bounds__(256, 4) void proj_kernel(
    const float* __restrict__ seq, const uint4* __restrict__ Bfrag,
    float* __restrict__ P, float* __restrict__ Lg)
{
    __shared__ unsigned Ah[2][BM][36];  // f16 pairs; 64 k/row = 32 uints + 4 pad
    const int t = threadIdx.x;
    const int wave = t >> 6, lane = t & 63;
    const int q = lane >> 4, r = lane & 15;
    const int cf0 = wave * 2;
    const int row0 = blockIdx.x * BM;

    floatx4 acc[2][2] = {{{0.f,0.f,0.f,0.f},{0.f,0.f,0.f,0.f}},
                         {{0.f,0.f,0.f,0.f},{0.f,0.f,0.f,0.f}}};

    // staging map: 8 threads/row x 32 rows; each thread loads 2 float4 per iter
    const int sr = t >> 3, sc = t & 7;
    const float4* gA = (const float4*)(seq + (size_t)(row0 + sr) * ND);
    float4 sv0 = gA[sc], sv1 = gA[sc + 8];

    const uint4* bp = Bfrag + (size_t)cf0 * 64 + lane;
    uint4 Bc0 = bp[0], Bc1 = bp[64], Bc2 = bp[512], Bc3 = bp[512 + 64];

    for (int i = 0; i < NIT; ++i) {
        H2U a01, a23, b01, b23;
        a01.h = __builtin_amdgcn_cvt_pkrtz(sv0.x, sv0.y);
        a23.h = __builtin_amdgcn_cvt_pkrtz(sv0.z, sv0.w);
        b01.h = __builtin_amdgcn_cvt_pkrtz(sv1.x, sv1.y);
        b23.h = __builtin_amdgcn_cvt_pkrtz(sv1.z, sv1.w);
        { uint2 u; u.x = a01.u; u.y = a23.u; *(uint2*)&Ah[i & 1][sr][sc * 2] = u; }
        { uint2 u; u.x = b01.u; u.y = b23.u; *(uint2*)&Ah[i & 1][sr][sc * 2 + 16] = u; }
        __syncthreads();                     // tile i visible (single barrier/iter)

        const int ni = (i + 1 < NIT) ? i + 1 : i;
        sv0 = gA[ni * 16 + sc];              // prefetch A tile i+1
        sv1 = gA[ni * 16 + sc + 8];
        const size_t nb = (size_t)ni * 1024;
        uint4 Bn0 = bp[nb], Bn1 = bp[nb + 64], Bn2 = bp[nb + 512], Bn3 = bp[nb + 512 + 64];

#pragma unroll
        for (int ksl = 0; ksl < 2; ++ksl) {
            U4H8 b0, b1;
            b0.v = ksl ? Bc2 : Bc0;
            b1.v = ksl ? Bc3 : Bc1;
#pragma unroll
            for (int rt = 0; rt < 2; ++rt) {
                U4H8 a;
                a.v = *(const uint4*)&Ah[i & 1][rt * 16 + r][ksl * 16 + q * 4];
                acc[rt][0] = __builtin_amdgcn_mfma_f32_16x16x32_f16(a.h8, b0.h8, acc[rt][0], 0, 0, 0);
                acc[rt][1] = __builtin_amdgcn_mfma_f32_16x16x32_f16(a.h8, b1.h8, acc[rt][1], 0, 0, 0);
            }
        }
        Bc0 = Bn0; Bc1 = Bn1; Bc2 = Bn2; Bc3 = Bn3;
    }

    // C/D layout: col = (cf0+c)*16 + r, row = row0 + rt*16 + q*4 + reg
#pragma unroll
    for (int rt = 0; rt < 2; ++rt) {
#pragma unroll
        for (int c = 0; c < 2; ++c) {
            const int col = (cf0 + c) * 16 + r;
            const int rowb = row0 + rt * 16 + q * 4;
            if (col < NH) {
#pragma unroll
                for (int reg = 0; reg < 4; ++reg)
                    P[(size_t)(rowb + reg) * LDP + col] = acc[rt][c][reg];
            } else if (col == NH) {
#pragma unroll
                for (int reg = 0; reg < 4; ++reg)
                    Lg[rowb + reg] = acc[rt][c][reg];
            }
        }
    }
}

// Kernel 2: ONE span per FULL wave, width-loop split across the two halves
// (half h handles rows 2j+h) -> 15-deep fully-unrolled load chain instead of
// 30. Softmax computed redundantly per half (identical by l32); the two
// half-accumulators merge with 4 width-64 shfl_xor adds. Fused bias+mask+tanh.
__global__ __launch_bounds__(256, 4) void span_kernel(
    const int* __restrict__ span_idx, const int* __restrict__ span_mask,
    const float* __restrict__ P, const float* __restrict__ Lg,
    const float* __restrict__ ffnn_b, float* __restrict__ out)
{
    const int wave = threadIdx.x >> 6;
    const int lane = threadIdx.x & 63;
    const int half = lane >> 5, l32 = lane & 31;
    const int gs = blockIdx.x * 4 + wave;          // [0, 4096)
    const int b = gs / NSP;
    const int st = span_idx[2 * gs];
    int w = span_idx[2 * gs + 1] - st;             // width in [1, MAXW]
    w = max(1, min(w, MAXW));

    // softmax over Lg (att_b cancels) — per-half, identical results
    float lg = (l32 < w) ? Lg[b * NS + st + l32] : -1e30f;
    float mx = lg;
#pragma unroll
    for (int off = 16; off > 0; off >>= 1) mx = fmaxf(mx, __shfl_xor(mx, off, 32));
    float e = (l32 < w) ? __expf(lg - mx) : 0.f;
    float sum = e;
#pragma unroll
    for (int off = 16; off > 0; off >>= 1) sum += __shfl_xor(sum, off, 32);
    float attn = e / sum;                          // 0 for l32 >= w

    const int cl = min(l32, 24);
    const float4* Pb4 = (const float4*)(P + ((size_t)b * NS + st) * LDP) + cl;
    float4 acc = {0.f, 0.f, 0.f, 0.f};
#pragma unroll
    for (int j = 0; j < MAXW / 2; ++j) {
        const int row = 2 * j + half;              // rows interleaved across halves
        float a = __shfl(attn, row, 32);           // row < 30 < 32 always
        if (row < w) {
            float4 v = Pb4[row * (LDP / 4)];
            acc.x += a * v.x; acc.y += a * v.y; acc.z += a * v.z; acc.w += a * v.w;
        }
    }
    // merge the two half-accumulators across the 32-lane boundary
    acc.x += __shfl_xor(acc.x, 32, 64);
    acc.y += __shfl_xor(acc.y, 32, 64);
    acc.z += __shfl_xor(acc.z, 32, 64);
    acc.w += __shfl_xor(acc.w, 32, 64);

    if (half == 0 && l32 < 25) {
        float m = (float)span_mask[gs];
        float4 bias = ((const float4*)ffnn_b)[cl];
        float4 o;
        o.x = tanhf(m * acc.x + bias.x);
        o.y = tanhf(m * acc.y + bias.y);
        o.z = tanhf(m * acc.z + bias.z);
        o.w = tanhf(m * acc.w + bias.w);
        *(float4*)(out + (size_t)gs * NH + 4 * l32) = o;
    }
}

extern "C" void kernel_launch(void* const* d_in, const int* in_sizes, int n_in,
                              void* d_out, int out_size, void* d_ws, size_t ws_size,
                              hipStream_t stream) {
    const float* seq      = (const float*)d_in[0];  // [B,S,D]
    const int*   span_idx = (const int*)d_in[1];    // [B,N,2] int32 on device
    const int*   span_msk = (const int*)d_in[2];    // [B,N]
    const float* att_w    = (const float*)d_in[3];  // [D,1]
    // d_in[4] = att_b: cancels inside softmax — unused
    const float* ffnn_w   = (const float*)d_in[5];  // [D,H]
    const float* ffnn_b   = (const float*)d_in[6];  // [H]
    float* out = (float*)d_out;                     // [B,N,H]

    char* ws = (char*)d_ws;
    size_t off = 0;
    float* P     = (float*)(ws + off); off += (size_t)NB * NS * LDP * 4;    // 6.82 MB
    uint4* Bfrag = (uint4*)(ws + off); off += (size_t)NKS * NCF * 64 * 16;  // 192 KB
    float* Lg    = (float*)(ws + off);                                      // 64 KB

    pack_b_kernel<<<NKS * NCF, 64, 0, stream>>>(ffnn_w, att_w, Bfrag);
    proj_kernel<<<(NB * NS) / BM, 256, 0, stream>>>(seq, Bfrag, P, Lg);
    span_kernel<<<(NB * NSP) / 4, 256, 0, stream>>>(span_idx, span_msk, P, Lg, ffnn_b, out);
}